// Round 2
// baseline (156.296 us; speedup 1.0000x reference)
//
#include <hip/hip_runtime.h>
#include <hip/hip_bf16.h>
#include <stdint.h>

#define B_   4
#define N_   10000
#define K_   16
#define D_   256
#define OUT_ 256
#define M_   (B_ * N_)          // 40000
#define CW   32                 // bf16 cols per y2 chunk (64-B rows)
#define NCH  8                  // chunks (one per XCD)
#define CHUNK_ELEMS ((size_t)N_ * B_ * CW)   // 1,280,000 ushorts = 2.56 MB
#define MT_  313                // ceil(40000 / 128) m-tiles
#define QSZ  32768              // ushorts per Wb quarter (8*128*32)

typedef __attribute__((ext_vector_type(8))) short          short8;    // MFMA frag
typedef __attribute__((ext_vector_type(8))) unsigned short ushort8;
typedef __attribute__((ext_vector_type(4))) float          f32x4;
typedef __attribute__((ext_vector_type(4))) unsigned short ushort4_t;

__device__ inline unsigned short f2bf(float f) {
    __hip_bfloat16 h = __float2bfloat16(f);
    return *reinterpret_cast<unsigned short*>(&h);
}
__device__ inline float bf2f(unsigned short u) {
    unsigned int v = ((unsigned int)u) << 16;
    return __builtin_bit_cast(float, v);
}

// ---------------------------------------------------------------------------
// wprep: W (256 x 512 f32, row o = [W1_o | W2_o]) -> Wb bf16 laid out EXACTLY
// in the linear order gemm_res's global_load_lds staging consumes:
//   Wb[((qtr*8 + ks)*128 + r)*32 + kw]  for output-row orow = qtr*128 + r,
//   k = ks*32 + kw, where orow<256 -> W1 (self), orow>=256 -> W2 (agg).
// 128 blocks, no dependency on x -> negligible critical-path cost.
// ---------------------------------------------------------------------------
__global__ __launch_bounds__(256) void wprep(const float* __restrict__ W,
                                             unsigned short* __restrict__ Wb) {
    const int g    = blockIdx.x * 256 + threadIdx.x;   // 0..32767
    const int orow = g >> 6;                           // 0..511
    const int k0   = (g & 63) * 4;
    const float* src = (orow < OUT_) ? (W + (size_t)orow * 512 + k0)
                                     : (W + (size_t)(orow - OUT_) * 512 + 256 + k0);
    const float4 v = *(const float4*)src;
    ushort4_t s;
    s.x = f2bf(v.x); s.y = f2bf(v.y); s.z = f2bf(v.z); s.w = f2bf(v.w);
    const size_t off = (size_t)(((orow >> 7) * 8 + (k0 >> 5)) * 128 + (orow & 127)) * 32
                     + (k0 & 31);
    *(ushort4_t*)(Wb + off) = s;
}

// ---------------------------------------------------------------------------
// gemm_res: y[m, o'] = x[m, :] . Wb[o', :]   (M=40000, K=256, N'=512)
// B-resident design: the block's 128x256 B quarter lives in LDS for the whole
// kernel (staged once, ONE barrier); A streams global->regs with depth-3
// prefetch; the K-loop has NO barriers, so A-load latency hides under MFMA.
// Block: 4 waves x 32 m-rows = 128 rows x 128 out-cols (quarter qtr).
// XCD mapping: all 4 quarters of an m-tile land on the same XCD ->
// x m-tile fetched from HBM once, siblings hit that XCD's L2.
//   qtr 0,1 -> y1 fp32 (self half);  qtr 2,3 -> y2 bf16 chunk-major (agg half)
// ---------------------------------------------------------------------------
__global__ __launch_bounds__(256) void gemm_res(const float* __restrict__ x,
                                                const unsigned short* __restrict__ Wb,
                                                float* __restrict__ y1,
                                                unsigned short* __restrict__ y2c) {
    __shared__ unsigned short Bs[8 * 128 * 32];   // 64 KB, [ks][row128][k32]

    const int tid  = threadIdx.x;
    const int w    = tid >> 6;
    const int lane = tid & 63;
    const int q    = lane >> 4;
    const int r16  = lane & 15;

    // block -> (m-tile g, quarter qtr), quarters of g share an XCD
    const int bi  = blockIdx.x;
    const int xcd = bi & 7;
    const int jj  = bi >> 3;
    const int g   = (jj >> 2) * 8 + xcd;
    const int qtr = jj & 3;
    if (g >= MT_) return;
    const int tile_m = g * 128;

    // ---- stage the 64-KB B quarter (linear: Wb layout already matches) ----
    {
        const unsigned short* wsrc = Wb + (size_t)qtr * QSZ + w * 512 + lane * 8;
        unsigned short*       ldst = Bs + w * 512;          // wave-uniform base
#pragma unroll
        for (int it = 0; it < 16; ++it) {
            __builtin_amdgcn_global_load_lds(
                (const __attribute__((address_space(1))) void*)(wsrc + it * 2048),
                (__attribute__((address_space(3))) void*)(ldst + it * 2048),
                16, 0, 0);
        }
    }
    __syncthreads();          // the only barrier

    // ---- A row pointers (per-lane fragment rows, clamped for the tail) ----
    int r0 = tile_m + w * 32 + r16;        // row-tile 0
    int r1 = r0 + 16;                      // row-tile 1
    if (r0 > M_ - 1) r0 = M_ - 1;
    if (r1 > M_ - 1) r1 = M_ - 1;
    const float* ap0 = x + (size_t)r0 * D_ + q * 8;
    const float* ap1 = x + (size_t)r1 * D_ + q * 8;

    f32x4 acc[2][8] = {};

    // depth-3 A prefetch buffers: slot s holds k-step (issued 3 ahead)
    float4 A0[3], A1[3], A2[3], A3[3];     // [t0 lo, t0 hi, t1 lo, t1 hi]
#pragma unroll
    for (int s = 0; s < 3; ++s) {
        A0[s] = *(const float4*)(ap0 + s * 32);
        A1[s] = *(const float4*)(ap0 + s * 32 + 4);
        A2[s] = *(const float4*)(ap1 + s * 32);
        A3[s] = *(const float4*)(ap1 + s * 32 + 4);
    }

#pragma unroll
    for (int ks = 0; ks < 8; ++ks) {
        const int sl = ks % 3;             // static after full unroll
        short8 a0, a1;
        a0[0] = (short)f2bf(A0[sl].x); a0[1] = (short)f2bf(A0[sl].y);
        a0[2] = (short)f2bf(A0[sl].z); a0[3] = (short)f2bf(A0[sl].w);
        a0[4] = (short)f2bf(A1[sl].x); a0[5] = (short)f2bf(A1[sl].y);
        a0[6] = (short)f2bf(A1[sl].z); a0[7] = (short)f2bf(A1[sl].w);
        a1[0] = (short)f2bf(A2[sl].x); a1[1] = (short)f2bf(A2[sl].y);
        a1[2] = (short)f2bf(A2[sl].z); a1[3] = (short)f2bf(A2[sl].w);
        a1[4] = (short)f2bf(A3[sl].x); a1[5] = (short)f2bf(A3[sl].y);
        a1[6] = (short)f2bf(A3[sl].z); a1[7] = (short)f2bf(A3[sl].w);
        if (ks + 3 < 8) {                  // refill the slot just consumed
            A0[sl] = *(const float4*)(ap0 + (ks + 3) * 32);
            A1[sl] = *(const float4*)(ap0 + (ks + 3) * 32 + 4);
            A2[sl] = *(const float4*)(ap1 + (ks + 3) * 32);
            A3[sl] = *(const float4*)(ap1 + (ks + 3) * 32 + 4);
        }
        const unsigned short* bbase = Bs + ks * 4096 + r16 * 32 + q * 8;
#pragma unroll
        for (int j = 0; j < 8; ++j) {
            const short8 b = *(const short8*)(bbase + j * 512);
            acc[0][j] = __builtin_amdgcn_mfma_f32_16x16x32_bf16(a0, b, acc[0][j], 0, 0, 0);
            acc[1][j] = __builtin_amdgcn_mfma_f32_16x16x32_bf16(a1, b, acc[1][j], 0, 0, 0);
        }
    }

    // ---- epilogue ----
    if (qtr < 2) {
        // y1 fp32, m-row-major, cols qtr*128 .. +128
#pragma unroll
        for (int i = 0; i < 2; ++i) {
#pragma unroll
            for (int reg = 0; reg < 4; ++reg) {
                const int m = tile_m + w * 32 + i * 16 + q * 4 + reg;
                if (m < M_) {
                    float* row = y1 + (size_t)m * OUT_ + qtr * 128;
#pragma unroll
                    for (int j = 0; j < 8; ++j)
                        row[j * 16 + r16] = acc[i][j][reg];
                }
            }
        }
    } else {
        // y2 bf16, chunk-major (gather-ready), chunks (qtr-2)*4 .. +4
        const int cbase = (qtr - 2) * 4;
#pragma unroll
        for (int i = 0; i < 2; ++i) {
#pragma unroll
            for (int reg = 0; reg < 4; ++reg) {
                const int m = tile_m + w * 32 + i * 16 + q * 4 + reg;
                if (m < M_) {
                    const int b = (m >= N_) + (m >= 2 * N_) + (m >= 3 * N_);
                    const int n = m - b * N_;
                    unsigned short* rb = y2c + (size_t)(n * B_ + b) * CW;
#pragma unroll
                    for (int j = 0; j < 8; ++j) {
                        const int c   = cbase + (j >> 1);
                        const int col = (j & 1) * 16 + r16;
                        rb[(size_t)c * CHUNK_ELEMS + col] = f2bf(acc[i][j][reg]);
                    }
                }
            }
        }
    }
}

// ---------------------------------------------------------------------------
// gather_out: out[b,n,o] = relu( y1[b,n,o] + (1/cnt) sum_k y2[b,neigh[n,k],o]
//                                + bias[o] )
// Proven L2-chunked gather (chunk c = blockIdx&7 -> XCD, 2.56-MB chunk
// resident in that XCD's L2; 16 independent 16-B gathers per thread), fused
// with the streaming y1 + bias + ReLU epilogue.
// ---------------------------------------------------------------------------
__global__ __launch_bounds__(256) void gather_out(const unsigned short* __restrict__ y2c,
                                                  const float* __restrict__ y1,
                                                  const int*   __restrict__ neigh,
                                                  const float* __restrict__ bias,
                                                  float* __restrict__ out) {
    const int c   = blockIdx.x & 7;
    const int g   = blockIdx.x >> 3;
    const int n0  = g * 16;
    const int tid = threadIdx.x;

    __shared__ int   idx_s[16 * K_];   // 256 ints
    __shared__ float inv_s[16];

    idx_s[tid] = neigh[n0 * K_ + tid];
    __syncthreads();
    if (tid < 16) {
        int cnt = 0;
#pragma unroll
        for (int k = 0; k < K_; ++k) cnt += idx_s[tid * K_ + k] >= 0 ? 1 : 0;
        inv_s[tid] = 1.0f / (float)(cnt > 1 ? cnt : 1);
    }
    __syncthreads();

    const int q  = tid & 3;          // 8-col group within the 32-col chunk
    const int tl = tid >> 2;         // task 0..63
    const int ns = tl >> 2;          // node_sub 0..15
    const int b  = tl & 3;           // batch

    const unsigned short* ycc = y2c + (size_t)c * CHUNK_ELEMS;

    int jj[K_];
#pragma unroll
    for (int k = 0; k < K_; ++k) jj[k] = idx_s[ns * K_ + k];

    // 16 independent 16-B gather loads from the L2-resident chunk
    ushort8 vv[K_];
#pragma unroll
    for (int k = 0; k < K_; ++k) {
        const int jc = jj[k] >= 0 ? jj[k] : 0;
        vv[k] = *(const ushort8*)(ycc + ((size_t)jc * B_ + b) * CW + q * 8);
    }

    // streaming self term + bias (issued while gathers are in flight)
    const size_t mo = (size_t)(b * N_ + n0 + ns) * OUT_ + c * CW + q * 8;
    const f32x4 s0 = *(const f32x4*)(y1 + mo);
    const f32x4 s1 = *(const f32x4*)(y1 + mo + 4);
    const f32x4 b0 = *(const f32x4*)(bias + c * CW + q * 8);
    const f32x4 b1 = *(const f32x4*)(bias + c * CW + q * 8 + 4);

    float acc[8] = {0.f, 0.f, 0.f, 0.f, 0.f, 0.f, 0.f, 0.f};
#pragma unroll
    for (int k = 0; k < K_; ++k) {
        const float m = jj[k] >= 0 ? 1.f : 0.f;
#pragma unroll
        for (int e = 0; e < 8; ++e) acc[e] += bf2f(vv[k][e]) * m;
    }
    const float inv = inv_s[ns];

    f32x4 o0, o1;
#pragma unroll
    for (int e = 0; e < 4; ++e) {
        float v0 = acc[e] * inv + s0[e] + b0[e];
        float v1 = acc[e + 4] * inv + s1[e] + b1[e];
        o0[e] = v0 > 0.f ? v0 : 0.f;
        o1[e] = v1 > 0.f ? v1 : 0.f;
    }
    // out is never re-read: nontemporal to avoid evicting the gather chunk
    __builtin_nontemporal_store(o0, (f32x4*)(out + mo));
    __builtin_nontemporal_store(o1, (f32x4*)(out + mo + 4));
}

// ---------------------------------------------------------------------------
extern "C" void kernel_launch(void* const* d_in, const int* in_sizes, int n_in,
                              void* d_out, int out_size, void* d_ws, size_t ws_size,
                              hipStream_t stream) {
    const float* x     = (const float*)d_in[0];   // (4, 10000, 256) fp32
    const int*   neigh = (const int*)d_in[1];     // (10000, 16) int32
    const float* W     = (const float*)d_in[2];   // (256, 512) fp32
    const float* bias  = (const float*)d_in[3];   // (256,) fp32
    float*       out   = (float*)d_out;           // (4, 10000, 256) fp32

    unsigned short* Wb  = (unsigned short*)d_ws;          // 512*256 bf16 = 0.26 MB
    float*          y1  = (float*)(Wb + 512 * D_);        // 40000*256 f32 = 40.96 MB
    unsigned short* y2c = (unsigned short*)(y1 + (size_t)M_ * OUT_);  // 8 x 2.56 MB

    wprep<<<128, 256, 0, stream>>>(W, Wb);
    gemm_res<<<(((MT_ + 7) / 8) * 8) * 4, 256, 0, stream>>>(x, Wb, y1, y2c);  // 1280
    gather_out<<<(N_ / 16) * NCH, 256, 0, stream>>>(y2c, y1, neigh, bias, out);
}

// Round 3
// 140.701 us; speedup vs baseline: 1.1108x; 1.1108x over previous
//
#include <hip/hip_runtime.h>
#include <hip/hip_bf16.h>
#include <stdint.h>

#define B_   4
#define N_   10000
#define K_   16
#define D_   256
#define OUT_ 256
#define M_   (B_ * N_)          // 40000
#define CW   32                 // bf16 cols per y2 chunk (64-B rows)
#define NCH  8                  // chunks (one per XCD)
#define CHUNK_ELEMS ((size_t)N_ * B_ * CW)   // 1,280,000 ushorts = 2.56 MB
#define TILES_ 625              // M / 64, exact
#define TPH    16384            // ushorts per (half,ks) B tile: 256 rows x 64 k

typedef __attribute__((ext_vector_type(8))) short          short8;    // MFMA frag
typedef __attribute__((ext_vector_type(8))) unsigned short ushort8;
typedef __attribute__((ext_vector_type(4))) float          f32x4;
typedef __attribute__((ext_vector_type(4))) unsigned short ushort4_t;

__device__ inline unsigned short f2bf(float f) {
    __hip_bfloat16 h = __float2bfloat16(f);
    return *reinterpret_cast<unsigned short*>(&h);
}
__device__ inline float bf2f(unsigned short u) {
    unsigned int v = ((unsigned int)u) << 16;
    return __builtin_bit_cast(float, v);
}

// ---------------------------------------------------------------------------
// wprep: W (256 x 512 f32, row o = [W1_o | W2_o]) -> Wb bf16, tiled
// [half][ks][...32KB...] where each 32-KB tile is the PRE-SWIZZLED image of
// the LDS B-buffer gemm3 stages linearly via global_load_lds:
//   LDS image desired:  Bs[(row*128 + k*2) ^ ((row&7)<<4)] = W'[row][k]
// (XOR swizzle makes the stride-128B b128 frag reads bank-conflict-free.)
// W'[row] = half==0 ? W1 row : W2 row;  k local to the ks-th 64-wide K slab.
// ---------------------------------------------------------------------------
__global__ __launch_bounds__(256) void wprep(const float* __restrict__ W,
                                             unsigned short* __restrict__ Wb) {
    const int g  = blockIdx.x * 256 + threadIdx.x;   // 0..32767
    const int h  = g >> 14;                          // half
    const int t  = g & 16383;
    const int ks = t >> 12;                          // k-slab 0..3
    const int rr = (t >> 4) & 255;                   // out-row 0..255
    const int kg = (t & 15) * 4;                     // k within slab, x4
    const float4 v = *(const float4*)(W + (size_t)rr * 512 + h * 256 + ks * 64 + kg);
    ushort4_t s;
    s.x = f2bf(v.x); s.y = f2bf(v.y); s.z = f2bf(v.z); s.w = f2bf(v.w);
    const int off = ((rr * 128 + kg * 2) ^ ((rr & 7) << 4)) >> 1;   // ushort idx
    *(ushort4_t*)(Wb + (size_t)(h * 4 + ks) * TPH + off) = s;
}

// ---------------------------------------------------------------------------
// gemm3: y[m, o'] = x[m, :] . W'[o', :]   (M=40000, K=256, N'=512)
// Tile 64m x 256n, 8 waves (512 thr), BK=64 -> 4 phases (half the barrier
// drains of round-1's BK=32). LDS 40 KB single-buffered (occupancy/TLP is
// the latency hider). A reg-staged fp32->bf16 with next-phase loads issued
// before compute. All LDS frag accesses XOR-swizzled (conflict-free b128).
//   half 0 -> y1 fp32 m-row-major (normal mfma(a,b))
//   half 1 -> y2 bf16 chunk-major via SWAPPED mfma(b,a): lane holds 4
//             consecutive o-cols -> packed 8-B ushort4 stores (was 64x 2-B).
// Block mapping keeps both halves of an m-tile on one XCD (x read once).
// ---------------------------------------------------------------------------
__global__ __launch_bounds__(512) void gemm3(const float* __restrict__ x,
                                             const unsigned short* __restrict__ Wb,
                                             float* __restrict__ y1,
                                             unsigned short* __restrict__ y2c) {
    __shared__ unsigned short As[64 * 64];    //  8 KB
    __shared__ unsigned short Bs[256 * 64];   // 32 KB

    const int tid  = threadIdx.x;
    const int w    = tid >> 6;
    const int lane = tid & 63;
    const int q    = lane >> 4;
    const int r16  = lane & 15;
    const int wm   = w >> 2;          // 0..1 : 32-row strip
    const int wn   = w & 3;           // 0..3 : 64-col strip

    // block -> (m-tile g, half), halves of g share an XCD
    const int bi   = blockIdx.x;
    const int xcd  = bi & 7;
    const int u    = bi >> 3;
    const int g    = (u >> 1) * 8 + xcd;
    const int half = u & 1;
    if (g >= TILES_) return;
    const int tile_m = g * 64;

    // ---- A staging coords: 64 rows x 64 k fp32; 512 thr x 16 f32 ----
    const int arow = tid >> 3;              // 0..63
    const int akg  = (tid & 7) * 8;         // 0,8,...,56
    const float* ap = x + (size_t)(tile_m + arow) * D_ + akg;
    const unsigned int awoff = (unsigned)((arow * 128 + akg * 2) ^ ((arow & 7) << 4));

    // ---- B staging: pure linear copy of the pre-swizzled 32-KB tile ----
    const unsigned short* wsrc0 = Wb + (size_t)(half * 4) * TPH + tid * 8;

    const unsigned int sw = (unsigned)((r16 & 7) << 4);   // frag-read swizzle

    f32x4 acc[2][4] = {};

    // prologue: load+stage phase 0
    float4 c0 = *(const float4*)ap;
    float4 c1 = *(const float4*)(ap + 4);
#pragma unroll
    for (int i2 = 0; i2 < 4; ++i2) {
        __builtin_amdgcn_global_load_lds(
            (const __attribute__((address_space(1))) void*)(wsrc0 + i2 * 4096),
            (__attribute__((address_space(3))) void*)(Bs + tid * 8 + i2 * 4096),
            16, 0, 0);
    }
    {
        ushort8 s;
        s[0] = f2bf(c0.x); s[1] = f2bf(c0.y); s[2] = f2bf(c0.z); s[3] = f2bf(c0.w);
        s[4] = f2bf(c1.x); s[5] = f2bf(c1.y); s[6] = f2bf(c1.z); s[7] = f2bf(c1.w);
        *(ushort8*)((char*)As + awoff) = s;
    }
    __syncthreads();

#pragma unroll
    for (int ks = 0; ks < 4; ++ks) {
        // issue next-phase A loads early (latency hides under MFMA)
        float4 n0, n1;
        if (ks < 3) {
            n0 = *(const float4*)(ap + (ks + 1) * 64);
            n1 = *(const float4*)(ap + (ks + 1) * 64 + 4);
        }

#pragma unroll
        for (int ksub = 0; ksub < 2; ++ksub) {
            short8 a[2], bf[4];
#pragma unroll
            for (int i = 0; i < 2; ++i) {
                const unsigned int ad =
                    (unsigned)((wm * 32 + i * 16 + r16) * 128 + ksub * 64 + q * 16) ^ sw;
                a[i] = *(const short8*)((const char*)As + ad);
            }
#pragma unroll
            for (int j = 0; j < 4; ++j) {
                const unsigned int bd =
                    (unsigned)((wn * 64 + j * 16 + r16) * 128 + ksub * 64 + q * 16) ^ sw;
                bf[j] = *(const short8*)((const char*)Bs + bd);
            }
            if (half == 0) {
#pragma unroll
                for (int i = 0; i < 2; ++i)
#pragma unroll
                    for (int j = 0; j < 4; ++j)
                        acc[i][j] = __builtin_amdgcn_mfma_f32_16x16x32_bf16(a[i], bf[j], acc[i][j], 0, 0, 0);
            } else {
#pragma unroll
                for (int i = 0; i < 2; ++i)
#pragma unroll
                    for (int j = 0; j < 4; ++j)
                        acc[i][j] = __builtin_amdgcn_mfma_f32_16x16x32_bf16(bf[j], a[i], acc[i][j], 0, 0, 0);
            }
        }

        if (ks < 3) {
            __syncthreads();            // all frag reads of the buffers done
            const unsigned short* wsrc = wsrc0 + (size_t)(ks + 1) * TPH;
#pragma unroll
            for (int i2 = 0; i2 < 4; ++i2) {
                __builtin_amdgcn_global_load_lds(
                    (const __attribute__((address_space(1))) void*)(wsrc + i2 * 4096),
                    (__attribute__((address_space(3))) void*)(Bs + tid * 8 + i2 * 4096),
                    16, 0, 0);
            }
            ushort8 s;
            s[0] = f2bf(n0.x); s[1] = f2bf(n0.y); s[2] = f2bf(n0.z); s[3] = f2bf(n0.w);
            s[4] = f2bf(n1.x); s[5] = f2bf(n1.y); s[6] = f2bf(n1.z); s[7] = f2bf(n1.w);
            *(ushort8*)((char*)As + awoff) = s;
            __syncthreads();            // staging visible (vmcnt0 + lgkm0)
        }
    }

    // ---- epilogue ----
    if (half == 0) {
        // D[row = q*4+reg (m), col = r16 (o)] : y1 fp32 m-row-major
#pragma unroll
        for (int i = 0; i < 2; ++i) {
#pragma unroll
            for (int reg = 0; reg < 4; ++reg) {
                const int m = tile_m + wm * 32 + i * 16 + q * 4 + reg;
                float* row = y1 + (size_t)m * OUT_ + wn * 64;
#pragma unroll
                for (int j = 0; j < 4; ++j)
                    row[j * 16 + r16] = acc[i][j][reg];
            }
        }
    } else {
        // swapped: D[row = q*4+reg (o), col = r16 (m)] -> packed ushort4
#pragma unroll
        for (int i = 0; i < 2; ++i) {
            const int m  = tile_m + wm * 32 + i * 16 + r16;
            const int bb = (m >= N_) + (m >= 2 * N_) + (m >= 3 * N_);
            const int n  = m - bb * N_;
            unsigned short* rb = y2c + (size_t)(n * B_ + bb) * CW;
#pragma unroll
            for (int j = 0; j < 4; ++j) {
                const int o2  = wn * 64 + j * 16 + q * 4;   // 4 consecutive cols
                const int cch = o2 >> 5;
                const int col = o2 & 31;
                ushort4_t p;
                p.x = f2bf(acc[i][j][0]); p.y = f2bf(acc[i][j][1]);
                p.z = f2bf(acc[i][j][2]); p.w = f2bf(acc[i][j][3]);
                *(ushort4_t*)(rb + (size_t)cch * CHUNK_ELEMS + col) = p;
            }
        }
    }
}

// ---------------------------------------------------------------------------
// gather_out: out[b,n,o] = relu( y1[b,n,o] + (1/cnt) sum_k y2[b,neigh[n,k],o]
//                                + bias[o] )
// Proven L2-chunked gather (chunk c = blockIdx&7 -> XCD, 2.56-MB chunk
// resident in that XCD's L2; 16 independent 16-B gathers per thread), fused
// with the streaming y1 + bias + ReLU epilogue.
// ---------------------------------------------------------------------------
__global__ __launch_bounds__(256) void gather_out(const unsigned short* __restrict__ y2c,
                                                  const float* __restrict__ y1,
                                                  const int*   __restrict__ neigh,
                                                  const float* __restrict__ bias,
                                                  float* __restrict__ out) {
    const int c   = blockIdx.x & 7;
    const int g   = blockIdx.x >> 3;
    const int n0  = g * 16;
    const int tid = threadIdx.x;

    __shared__ int   idx_s[16 * K_];   // 256 ints
    __shared__ float inv_s[16];

    idx_s[tid] = neigh[n0 * K_ + tid];
    __syncthreads();
    if (tid < 16) {
        int cnt = 0;
#pragma unroll
        for (int k = 0; k < K_; ++k) cnt += idx_s[tid * K_ + k] >= 0 ? 1 : 0;
        inv_s[tid] = 1.0f / (float)(cnt > 1 ? cnt : 1);
    }
    __syncthreads();

    const int q  = tid & 3;          // 8-col group within the 32-col chunk
    const int tl = tid >> 2;         // task 0..63
    const int ns = tl >> 2;          // node_sub 0..15
    const int b  = tl & 3;           // batch

    const unsigned short* ycc = y2c + (size_t)c * CHUNK_ELEMS;

    int jj[K_];
#pragma unroll
    for (int k = 0; k < K_; ++k) jj[k] = idx_s[ns * K_ + k];

    // 16 independent 16-B gather loads from the L2-resident chunk
    ushort8 vv[K_];
#pragma unroll
    for (int k = 0; k < K_; ++k) {
        const int jc = jj[k] >= 0 ? jj[k] : 0;
        vv[k] = *(const ushort8*)(ycc + ((size_t)jc * B_ + b) * CW + q * 8);
    }

    // streaming self term + bias (issued while gathers are in flight)
    const size_t mo = (size_t)(b * N_ + n0 + ns) * OUT_ + c * CW + q * 8;
    const f32x4 s0 = *(const f32x4*)(y1 + mo);
    const f32x4 s1 = *(const f32x4*)(y1 + mo + 4);
    const f32x4 b0 = *(const f32x4*)(bias + c * CW + q * 8);
    const f32x4 b1 = *(const f32x4*)(bias + c * CW + q * 8 + 4);

    float acc[8] = {0.f, 0.f, 0.f, 0.f, 0.f, 0.f, 0.f, 0.f};
#pragma unroll
    for (int k = 0; k < K_; ++k) {
        const float m = jj[k] >= 0 ? 1.f : 0.f;
#pragma unroll
        for (int e = 0; e < 8; ++e) acc[e] += bf2f(vv[k][e]) * m;
    }
    const float inv = inv_s[ns];

    f32x4 o0, o1;
#pragma unroll
    for (int e = 0; e < 4; ++e) {
        float v0 = acc[e] * inv + s0[e] + b0[e];
        float v1 = acc[e + 4] * inv + s1[e] + b1[e];
        o0[e] = v0 > 0.f ? v0 : 0.f;
        o1[e] = v1 > 0.f ? v1 : 0.f;
    }
    // out is never re-read: nontemporal to avoid evicting the gather chunk
    __builtin_nontemporal_store(o0, (f32x4*)(out + mo));
    __builtin_nontemporal_store(o1, (f32x4*)(out + mo + 4));
}

// ---------------------------------------------------------------------------
extern "C" void kernel_launch(void* const* d_in, const int* in_sizes, int n_in,
                              void* d_out, int out_size, void* d_ws, size_t ws_size,
                              hipStream_t stream) {
    const float* x     = (const float*)d_in[0];   // (4, 10000, 256) fp32
    const int*   neigh = (const int*)d_in[1];     // (10000, 16) int32
    const float* W     = (const float*)d_in[2];   // (256, 512) fp32
    const float* bias  = (const float*)d_in[3];   // (256,) fp32
    float*       out   = (float*)d_out;           // (4, 10000, 256) fp32

    unsigned short* Wb  = (unsigned short*)d_ws;          // 8*16384 ushorts = 0.26 MB
    float*          y1  = (float*)(Wb + 8 * TPH);         // 40000*256 f32 = 40.96 MB
    unsigned short* y2c = (unsigned short*)(y1 + (size_t)M_ * OUT_);  // 8 x 2.56 MB

    wprep<<<128, 256, 0, stream>>>(W, Wb);
    gemm3<<<158 * 8, 256 * 2, 0, stream>>>(x, Wb, y1, y2c);   // 1264 blocks, 512 thr
    gather_out<<<(N_ / 16) * NCH, 256, 0, stream>>>(y2c, y1, neigh, bias, out);
}